// Round 1
// baseline (6512.067 us; speedup 1.0000x reference)
//
#include <hip/hip_runtime.h>

using short8 = __attribute__((ext_vector_type(8))) short;
using f32x4  = __attribute__((ext_vector_type(4))) float;

typedef unsigned short u16;
typedef unsigned int   u32;

#define T_SEQ 256
#define BATCH 64
#define INP   256
#define HID   1024
#define GDIM  4096
#define KC    1280   // HID + INP
#define OUTD  1024

__device__ __forceinline__ u16 f2bf(float f){
  union { float f; u32 u; } v; v.f = f;
  u32 r = v.u + 0x7fffu + ((v.u >> 16) & 1u);
  return (u16)(r >> 16);
}
__device__ __forceinline__ float sigm(float x){ return 1.f/(1.f+__expf(-x)); }
__device__ __forceinline__ float tanhf_(float x){ return 1.f - 2.f/(__expf(2.f*x)+1.f); }

// ---------------------------------------------------------------------------
// Prep: build combined recurrent weights, bf16, gate-interleaved, transposed.
// Wc[n][k], n = 4*j + gate (j = h column, gate in {i,f,o,cg}), k in [0,1280):
//   k <  1024 -> Wh[k][gate*1024 + j]
//   k >= 1024 -> Wx[k-1024][gate*1024 + j]
// ---------------------------------------------------------------------------
__global__ void build_wc(const float* __restrict__ WhF, const float* __restrict__ WxF,
                         const float* __restrict__ WhB, const float* __restrict__ WxB,
                         u16* __restrict__ WcF, u16* __restrict__ WcB)
{
  const int z = blockIdx.z; const int dir = z >> 2, gate = z & 3;
  const float* Wh = dir ? WhB : WhF;
  const float* Wx = dir ? WxB : WxF;
  u16* Wc = dir ? WcB : WcF;
  const int k0 = blockIdx.x * 64, j0 = blockIdx.y * 64;
  __shared__ float tile[64][65];
  const int t = threadIdx.x;
  #pragma unroll
  for (int i = 0; i < 16; ++i) {
    int idx = i*256 + t; int kr = idx >> 6, jc = idx & 63;
    int k = k0 + kr;
    float v = (k < HID) ? Wh[(size_t)k*GDIM + gate*HID + j0 + jc]
                        : Wx[(size_t)(k-HID)*GDIM + gate*HID + j0 + jc];
    tile[kr][jc] = v;
  }
  __syncthreads();
  #pragma unroll
  for (int i = 0; i < 16; ++i) {
    int idx = i*256 + t; int jc = idx >> 6, kr = idx & 63;
    int n = 4*(j0 + jc) + gate;
    Wc[(size_t)n*KC + k0 + kr] = f2bf(tile[kr][jc]);
  }
}

// W_fc [2048][1024] f32 -> WfcT [1024][2048] bf16 (transposed)
__global__ void build_wfc(const float* __restrict__ Wfc, u16* __restrict__ WfcT)
{
  const int k0 = blockIdx.x * 64;  // over 2048
  const int n0 = blockIdx.y * 64;  // over 1024
  __shared__ float tile[64][65];
  const int t = threadIdx.x;
  #pragma unroll
  for (int i = 0; i < 16; ++i) {
    int idx = i*256 + t; int kr = idx >> 6, nc = idx & 63;
    tile[kr][nc] = Wfc[(size_t)(k0+kr)*OUTD + n0 + nc];
  }
  __syncthreads();
  #pragma unroll
  for (int i = 0; i < 16; ++i) {
    int idx = i*256 + t; int nc = idx >> 6, kr = idx & 63;
    WfcT[(size_t)(n0+nc)*2048 + k0 + kr] = f2bf(tile[kr][nc]);
  }
}

// x f32 -> bf16
__global__ void conv_x(const float* __restrict__ x, u16* __restrict__ xb, int n)
{
  int i = (blockIdx.x * blockDim.x + threadIdx.x) * 4;
  if (i < n) {
    float4 v = *(const float4*)(x + i);
    u32 lo = (u32)f2bf(v.x) | ((u32)f2bf(v.y) << 16);
    u32 hi = (u32)f2bf(v.z) | ((u32)f2bf(v.w) << 16);
    *(uint2*)(xb + i) = make_uint2(lo, hi);
  }
}

// ---------------------------------------------------------------------------
// One LSTM timestep, both directions. Block = 256 threads (4 waves).
// blockIdx.x = N-tile (128 gate cols = 32 h cols), blockIdx.y = direction.
// g[64 x 128] = [h_prev | x_t] (64x1280, bf16) @ Wc_tile (1280x128, bf16)
// then fused cell update for this block's 32 h columns.
// ---------------------------------------------------------------------------
__global__ __launch_bounds__(256) void lstm_step(
    const u16* __restrict__ WcF, const u16* __restrict__ WcB,
    const u16* __restrict__ xb,
    u16* __restrict__ hF, u16* __restrict__ hB,
    float* __restrict__ cF, float* __restrict__ cB,
    const float* __restrict__ bF, const float* __restrict__ bB,
    u16* __restrict__ hs, float* __restrict__ out_tail, int s)
{
  const int dir = blockIdx.y;
  const int n0  = blockIdx.x * 128;
  const int tt  = dir ? (T_SEQ - 1 - s) : s;
  const u16*  Wc    = dir ? WcB : WcF;
  const float* bias = dir ? bB  : bF;
  u16* hbuf = dir ? hB : hF;
  const u16* hprev = hbuf + (s & 1) * (BATCH * HID);
  u16*       hnext = hbuf + ((s + 1) & 1) * (BATCH * HID);
  float* cbuf = dir ? cB : cF;
  const u16* xrow = xb + (size_t)tt * BATCH * INP;

  __shared__ __align__(16) u16 As[64 * 32];
  __shared__ __align__(16) u16 Bs[128 * 32];
  __shared__ __align__(16) float gs[64 * 128];

  const int tid  = threadIdx.x;
  const int w    = tid >> 6, lane = tid & 63;
  const int r    = lane & 15, q = lane >> 4;
  const int wy   = w >> 1, wx = w & 1;   // wave tile: rows 32*wy, cols 64*wx

  f32x4 acc[2][4];
  #pragma unroll
  for (int a = 0; a < 2; ++a)
    #pragma unroll
    for (int b = 0; b < 4; ++b) acc[a][b] = (f32x4)(0.f);

  const int ar = tid >> 2, ak = (tid & 3) * 8;   // A stage: 64 rows x 32 k
  const int bn = tid >> 1, bk = (tid & 1) * 16;  // B stage: 128 rows x 32 k

  for (int k0 = 0; k0 < KC; k0 += 32) {
    __syncthreads();
    { // stage A chunk: [h | x_t] rows
      const u16* src = (k0 < HID) ? (hprev + (size_t)ar * HID + k0 + ak)
                                  : (xrow  + (size_t)ar * INP + (k0 - HID) + ak);
      *(short8*)&As[ar * 32 + ak] = *(const short8*)src;
    }
    { // stage B chunk: Wc rows (N-major, K contiguous)
      const u16* src = Wc + (size_t)(n0 + bn) * KC + k0 + bk;
      *(short8*)&Bs[bn * 32 + bk]     = *(const short8*)src;
      *(short8*)&Bs[bn * 32 + bk + 8] = *(const short8*)(src + 8);
    }
    __syncthreads();

    short8 af[2];
    #pragma unroll
    for (int mt = 0; mt < 2; ++mt)
      af[mt] = *(const short8*)&As[(wy * 32 + mt * 16 + r) * 32 + q * 8];
    #pragma unroll
    for (int nt = 0; nt < 4; ++nt) {
      short8 bf = *(const short8*)&Bs[(wx * 64 + nt * 16 + r) * 32 + q * 8];
      acc[0][nt] = __builtin_amdgcn_mfma_f32_16x16x32_bf16(af[0], bf, acc[0][nt], 0, 0, 0);
      acc[1][nt] = __builtin_amdgcn_mfma_f32_16x16x32_bf16(af[1], bf, acc[1][nt], 0, 0, 0);
    }
  }
  __syncthreads();

  // spill g to LDS (D layout: row = 4q+reg, col = r within each 16x16 tile)
  #pragma unroll
  for (int mt = 0; mt < 2; ++mt)
    #pragma unroll
    for (int nt = 0; nt < 4; ++nt)
      #pragma unroll
      for (int reg = 0; reg < 4; ++reg) {
        int m = wy * 32 + mt * 16 + q * 4 + reg;
        int n = wx * 64 + nt * 16 + r;
        gs[m * 128 + n] = acc[mt][nt][reg];
      }
  __syncthreads();

  // fused cell update: 64 rows x 32 h-cols
  #pragma unroll
  for (int i = 0; i < 8; ++i) {
    int job = i * 256 + tid;
    int row = job >> 5, jl = job & 31;
    int jg  = (n0 >> 2) + jl;   // global h column
    float gi = gs[row * 128 + jl * 4 + 0] + bias[0 * HID + jg];
    float gf = gs[row * 128 + jl * 4 + 1] + bias[1 * HID + jg];
    float go = gs[row * 128 + jl * 4 + 2] + bias[2 * HID + jg];
    float gc = gs[row * 128 + jl * 4 + 3] + bias[3 * HID + jg];
    float co = cbuf[row * HID + jg];
    float cn = sigm(gf) * co + sigm(gi) * tanhf_(gc);
    float hn = sigm(go) * tanhf_(cn);
    cbuf[row * HID + jg] = cn;
    u16 hb = f2bf(hn);
    hnext[row * HID + jg] = hb;
    hs[((size_t)tt * BATCH + row) * 2048 + dir * HID + jg] = hb;
    if (s == T_SEQ - 1) {
      out_tail[dir * (BATCH * HID) + row * HID + jg] = hn;                       // hF / hB
      out_tail[2 * (BATCH * HID) + dir * (BATCH * HID) + row * HID + jg] = cn;   // cF / cB
    }
  }
}

// ---------------------------------------------------------------------------
// Final FC: out[16384][1024] = hs[16384][2048] @ WfcT^T + b_fc, f32 out.
// ---------------------------------------------------------------------------
__global__ __launch_bounds__(256) void fc_kernel(
    const u16* __restrict__ hs, const u16* __restrict__ WfcT,
    const float* __restrict__ bfc, float* __restrict__ out)
{
  const int m0 = blockIdx.x * 128, n0 = blockIdx.y * 128;
  __shared__ __align__(16) u16 As[128 * 32];
  __shared__ __align__(16) u16 Bs[128 * 32];
  const int tid = threadIdx.x;
  const int w = tid >> 6, lane = tid & 63;
  const int r = lane & 15, q = lane >> 4;
  const int wy = w >> 1, wx = w & 1;  // wave 64x64

  f32x4 acc[4][4];
  #pragma unroll
  for (int a = 0; a < 4; ++a)
    #pragma unroll
    for (int b = 0; b < 4; ++b) acc[a][b] = (f32x4)(0.f);

  const int lr = tid >> 1, lk = (tid & 1) * 16;

  for (int k0 = 0; k0 < 2048; k0 += 32) {
    __syncthreads();
    *(short8*)&As[lr * 32 + lk]     = *(const short8*)(hs   + (size_t)(m0 + lr) * 2048 + k0 + lk);
    *(short8*)&As[lr * 32 + lk + 8] = *(const short8*)(hs   + (size_t)(m0 + lr) * 2048 + k0 + lk + 8);
    *(short8*)&Bs[lr * 32 + lk]     = *(const short8*)(WfcT + (size_t)(n0 + lr) * 2048 + k0 + lk);
    *(short8*)&Bs[lr * 32 + lk + 8] = *(const short8*)(WfcT + (size_t)(n0 + lr) * 2048 + k0 + lk + 8);
    __syncthreads();

    short8 af[4], bf[4];
    #pragma unroll
    for (int mt = 0; mt < 4; ++mt)
      af[mt] = *(const short8*)&As[(wy * 64 + mt * 16 + r) * 32 + q * 8];
    #pragma unroll
    for (int nt = 0; nt < 4; ++nt)
      bf[nt] = *(const short8*)&Bs[(wx * 64 + nt * 16 + r) * 32 + q * 8];
    #pragma unroll
    for (int mt = 0; mt < 4; ++mt)
      #pragma unroll
      for (int nt = 0; nt < 4; ++nt)
        acc[mt][nt] = __builtin_amdgcn_mfma_f32_16x16x32_bf16(af[mt], bf[nt], acc[mt][nt], 0, 0, 0);
  }

  #pragma unroll
  for (int mt = 0; mt < 4; ++mt)
    #pragma unroll
    for (int nt = 0; nt < 4; ++nt)
      #pragma unroll
      for (int reg = 0; reg < 4; ++reg) {
        int m = m0 + wy * 64 + mt * 16 + q * 4 + reg;
        int n = n0 + wx * 64 + nt * 16 + r;
        out[(size_t)m * OUTD + n] = acc[mt][nt][reg] + bfc[n];
      }
}

// ---------------------------------------------------------------------------
extern "C" void kernel_launch(void* const* d_in, const int* in_sizes, int n_in,
                              void* d_out, int out_size, void* d_ws, size_t ws_size,
                              hipStream_t stream)
{
  const float* x   = (const float*)d_in[0];
  const float* WxF = (const float*)d_in[1];
  const float* WhF = (const float*)d_in[2];
  const float* bF  = (const float*)d_in[3];
  const float* WxB = (const float*)d_in[4];
  const float* WhB = (const float*)d_in[5];
  const float* bB  = (const float*)d_in[6];
  const float* Wfc = (const float*)d_in[7];
  const float* bfc = (const float*)d_in[8];
  float* out = (float*)d_out;

  char* ws = (char*)d_ws;
  u16*  WcF  = (u16*)(ws + 0);          // 4096*1280*2 = 10485760
  u16*  WcB  = (u16*)(ws + 10485760);   // 10485760
  u16*  WfcT = (u16*)(ws + 20971520);   // 1024*2048*2 = 4194304
  u16*  xb   = (u16*)(ws + 25165824);   // 256*64*256*2 = 8388608
  u16*  hF   = (u16*)(ws + 33554432);   // 2*64*1024*2 = 262144
  u16*  hB   = (u16*)(ws + 33816576);   // 262144
  float* cF  = (float*)(ws + 34078720); // 64*1024*4 = 262144
  float* cB  = (float*)(ws + 34340864); // 262144
  u16*  hs   = (u16*)(ws + 34603008);   // 256*64*2048*2 = 67108864
  // total ws use: 101711872 bytes

  // zero h double-buffers and c states (re-initialized every call)
  hipMemsetAsync(ws + 33554432, 0, 1048576, stream);

  build_wc <<<dim3(KC/64, HID/64, 8), 256, 0, stream>>>(WhF, WxF, WhB, WxB, WcF, WcB);
  build_wfc<<<dim3(2048/64, OUTD/64), 256, 0, stream>>>(Wfc, WfcT);
  conv_x   <<<(T_SEQ*BATCH*INP)/4/256, 256, 0, stream>>>(x, xb, T_SEQ*BATCH*INP);

  for (int s = 0; s < T_SEQ; ++s)
    lstm_step<<<dim3(GDIM/128, 2), 256, 0, stream>>>(WcF, WcB, xb, hF, hB, cF, cB,
                                                     bF, bB, hs, out + 16777216, s);

  fc_kernel<<<dim3(16384/128, OUTD/128), 256, 0, stream>>>(hs, WfcT, bfc, out);
}